// Round 1
// 196.167 us; speedup vs baseline: 1.0580x; 1.0580x over previous
//
#include <hip/hip_runtime.h>
#include <hip/hip_fp16.h>

// Problem constants
#define B_  8
#define C_  64
#define N_  2000
#define T_  12
#define E_  64000
#define HID_ 32
#define NTILE 16

typedef float f32x4 __attribute__((ext_vector_type(4)));
typedef float f32x2 __attribute__((ext_vector_type(2)));

union H4 {            // 4 halves <-> 8 bytes
  __half2 h[2];
  f32x2   f;
};

// ---------------------------------------------------------------------------
// Kernel 0: fold W3/W4/conv_w/scales into M1/M2 (64x64 each, fp32)
//   M1[c',c] = W1s * sum_{h<32} W3[c',h] * conv_w[c,h]
//   M2[c',c] = W2s * sum_{h<32} W4[c',h] * conv_w[c,32+h]
// ---------------------------------------------------------------------------
__global__ __launch_bounds__(256) void fold_kernel(
    const float* __restrict__ W3, const float* __restrict__ W4,
    const float* __restrict__ conv_w,
    const float* __restrict__ w1s, const float* __restrict__ w2s,
    float* __restrict__ M1, float* __restrict__ M2) {
  int i = blockIdx.x * 256 + threadIdx.x;   // 0..4095
  if (i >= 64 * 64) return;
  int cp = i >> 6;   // c' (row of W3/W4)
  int c  = i & 63;   // output channel (row of conv_w)
  const float* w3 = W3 + cp * HID_;
  const float* w4 = W4 + cp * HID_;
  const float* cw = conv_w + c * (2 * HID_);
  float s1 = 0.f, s2 = 0.f;
#pragma unroll
  for (int h = 0; h < HID_; ++h) {
    s1 += w3[h] * cw[h];
    s2 += w4[h] * cw[HID_ + h];
  }
  M1[i] = s1 * w1s[0];
  M2[i] = s2 * w2s[0];
}

// ---------------------------------------------------------------------------
// Kernel 1: per-node transform -> fp16 A/Bv.
//   lt[b,n,c'] = sum_t x[b,c',n,t] * (t/11)
//   rt[b,n,c'] = S - lt   (t_dn = 1 - t_up)
//   A[b,n,c]  = sum_c' lt * M1[c',c]   (stored fp16)
//   Bv[b,n,c] = sum_c' rt * M2[c',c]   (stored fp16)
// Block: 256 threads, one b and NTILE=16 nodes. Grid = 8 * 125.
//
// Change this round: M1/M2 staged to LDS (prefetched into regs before
// stage 1 so L2 latency hides under the x time-reduction). Stage 2 was
// L1-BW bound on M re-reads (32 B/thread/iter * 64 iters = 2 KB/thread
// of L1 traffic); LDS gives ~4x the per-CU read BW, conflict-free
// pattern (16-lane b128 span = 2-way = free; upper groups broadcast).
// LDS 8 -> 40 KB/block: occupancy already grid-limited at ~4 blk/CU.
// ---------------------------------------------------------------------------
__global__ __launch_bounds__(256) void node_kernel(
    const float* __restrict__ x,
    const float* __restrict__ M1, const float* __restrict__ M2,
    __half* __restrict__ Ah, __half* __restrict__ Bh) {
  __shared__ float lt[C_ * NTILE];
  __shared__ float rt[C_ * NTILE];
  __shared__ float M1s[C_ * 64];   // 16 KB
  __shared__ float M2s[C_ * 64];   // 16 KB

  const int blk = blockIdx.x;
  const int b   = blk / (N_ / NTILE);      // /125
  const int n0  = (blk % (N_ / NTILE)) * NTILE;
  const int tid = threadIdx.x;

  // ---- prefetch M1/M2 into registers (4096 floats each, 16 f32/thread)
  f32x4 rm1[4], rm2[4];
#pragma unroll
  for (int k = 0; k < 4; ++k) {
    rm1[k] = ((const f32x4*)M1)[tid + k * 256];
    rm2[k] = ((const f32x4*)M2)[tid + k * 256];
  }

  // ---- stage 1: time reduction (64 c' x 16 n = 1024 tasks, 4 per thread)
#pragma unroll
  for (int it = 0; it < (C_ * NTILE) / 256; ++it) {
    int task = it * 256 + tid;
    int cp = task >> 4;        // c'
    int nn = task & 15;        // node within tile
    const float* p = x + ((size_t)(b * C_ + cp) * N_ + (n0 + nn)) * T_;
    f32x4 v0 = __builtin_nontemporal_load((const f32x4*)(p));
    f32x4 v1 = __builtin_nontemporal_load((const f32x4*)(p + 4));
    f32x4 v2 = __builtin_nontemporal_load((const f32x4*)(p + 8));
    float s  = v0[0] + v0[1] + v0[2] + v0[3]
             + v1[0] + v1[1] + v1[2] + v1[3]
             + v2[0] + v2[1] + v2[2] + v2[3];
    float su = (v0[1] * 1.f + v0[2] * 2.f + v0[3] * 3.f
              + v1[0] * 4.f + v1[1] * 5.f + v1[2] * 6.f + v1[3] * 7.f
              + v2[0] * 8.f + v2[1] * 9.f + v2[2] * 10.f + v2[3] * 11.f)
             * (1.0f / 11.0f);
    lt[cp * NTILE + nn] = su;       // t_up weighting
    rt[cp * NTILE + nn] = s - su;   // t_dn = 1 - t_up
  }

  // ---- commit M regs to LDS (covered by the same barrier as lt/rt)
#pragma unroll
  for (int k = 0; k < 4; ++k) {
    ((f32x4*)M1s)[tid + k * 256] = rm1[k];
    ((f32x4*)M2s)[tid + k * 256] = rm2[k];
  }
  __syncthreads();

  // ---- stage 2: 64-deep dot with M1/M2 from LDS. tid = cg + 16*nn.
  const int cg = tid & 15;   // 4 consecutive c per thread
  const int nn = tid >> 4;
  float a0 = 0.f, a1 = 0.f, a2 = 0.f, a3 = 0.f;
  float b0 = 0.f, b1 = 0.f, b2 = 0.f, b3 = 0.f;
#pragma unroll 8
  for (int cp = 0; cp < C_; ++cp) {
    float lv = lt[cp * NTILE + nn];   // broadcast across cg lanes
    float rv = rt[cp * NTILE + nn];
    f32x4 m1 = *(const f32x4*)(M1s + cp * 64 + cg * 4);
    f32x4 m2 = *(const f32x4*)(M2s + cp * 64 + cg * 4);
    a0 += lv * m1[0]; a1 += lv * m1[1]; a2 += lv * m1[2]; a3 += lv * m1[3];
    b0 += rv * m2[0]; b1 += rv * m2[1]; b2 += rv * m2[2]; b3 += rv * m2[3];
  }
  size_t row = ((size_t)b * N_ + (n0 + nn)) * 64;
  H4 ua, ub;
  ua.h[0] = __floats2half2_rn(a0, a1); ua.h[1] = __floats2half2_rn(a2, a3);
  ub.h[0] = __floats2half2_rn(b0, b1); ub.h[1] = __floats2half2_rn(b2, b3);
  *(f32x2*)(Ah + row + cg * 4) = ua.f;
  *(f32x2*)(Bh + row + cg * 4) = ub.f;
}

// ---------------------------------------------------------------------------
// Kernel 2: edge gather + add.
//   out[b,e,c] = A[b,idx[e],c] + Bv[b,idy[e],c] + conv_b[c]
// 16 threads per (b,e) pair; each reads 8 B from A and Bv (fp16 rows of
// 128 B -> one fully-coalesced 128 B read per pair per array), writes one
// float4 of out with a NONTEMPORAL store (don't thrash L2 holding A/Bv).
// ---------------------------------------------------------------------------
__global__ __launch_bounds__(256) void gather_kernel(
    const __half* __restrict__ Ah, const __half* __restrict__ Bh,
    const int* __restrict__ idx, const int* __restrict__ idy,
    const float* __restrict__ conv_b, float* __restrict__ out) {
  int g  = blockIdx.x * 256 + threadIdx.x;  // 0 .. B*E*16-1
  int c4 = g & 15;
  int p  = g >> 4;              // (b,e) pair, 0..511999
  int b  = p / E_;
  int e  = p - b * E_;
  int ni = idx[e];
  int nj = idy[e];
  H4 ua = *(const H4*)(Ah + (size_t)(b * N_ + ni) * 64 + c4 * 4);
  H4 ub = *(const H4*)(Bh + (size_t)(b * N_ + nj) * 64 + c4 * 4);
  float2 a01 = __half22float2(ua.h[0]);
  float2 a23 = __half22float2(ua.h[1]);
  float2 b01 = __half22float2(ub.h[0]);
  float2 b23 = __half22float2(ub.h[1]);
  f32x4 cb = *(const f32x4*)(conv_b + c4 * 4);
  f32x4 o;
  o[0] = a01.x + b01.x + cb[0];
  o[1] = a01.y + b01.y + cb[1];
  o[2] = a23.x + b23.x + cb[2];
  o[3] = a23.y + b23.y + cb[3];
  __builtin_nontemporal_store(o, (f32x4*)(out + (size_t)p * 64 + c4 * 4));
}

// ---------------------------------------------------------------------------
extern "C" void kernel_launch(void* const* d_in, const int* in_sizes, int n_in,
                              void* d_out, int out_size, void* d_ws, size_t ws_size,
                              hipStream_t stream) {
  const float* x      = (const float*)d_in[0];
  const int*   idx    = (const int*)  d_in[1];
  const int*   idy    = (const int*)  d_in[2];
  const float* w1s    = (const float*)d_in[3];
  const float* w2s    = (const float*)d_in[4];
  const float* W3     = (const float*)d_in[5];
  const float* W4     = (const float*)d_in[6];
  const float* conv_w = (const float*)d_in[7];
  const float* conv_b = (const float*)d_in[8];
  float* out = (float*)d_out;

  float*  W  = (float*)d_ws;
  float*  M1 = W;                         // 4096 floats
  float*  M2 = W + 4096;                  // 4096 floats
  __half* Ah = (__half*)(W + 8192);       // B*N*64 halves = 2 MB
  __half* Bh = Ah + (size_t)B_ * N_ * 64;

  fold_kernel<<<16, 256, 0, stream>>>(W3, W4, conv_w, w1s, w2s, M1, M2);
  node_kernel<<<B_ * (N_ / NTILE), 256, 0, stream>>>(x, M1, M2, Ah, Bh);
  gather_kernel<<<(B_ * E_ * 16) / 256, 256, 0, stream>>>(Ah, Bh, idx, idy, conv_b, out);
}